// Round 11
// baseline (282.906 us; speedup 1.0000x reference)
//
#include <hip/hip_runtime.h>
#include <hip/hip_fp16.h>

// ---------------------------------------------------------------------------
// GCN 2-layer (PyG GCNConv) on MI355X — R26 (diagnostic round).
// R24 post-mortem: finalize-TLP restructure neutral (280.9 vs 279.6) —
// branch (b) AGAIN: finalize also not the mass. Component model now fails:
// modeled sum ~190us vs measured 281us -> ~90us unexplained, and top-5 is
// monopolized by agg1 iterations (~52us), hiding every other kernel.
// R26 single change-unit: SPLIT k_agg1 into k_agg1_lo ([0,N/2)) and
// k_agg1_hi ([N/2,N)), bodies byte-identical frozen R16 form. Each half
// ~26-28us -> vacates top-5 slots -> profiler reveals true #2/#3/#4.
// Cost: +1 launch (~3us). Everything else byte-identical to R24.
// Predict: total ~281-285; halves ~27us each, FETCH ~79MB each.
// Pre-registered: (a) any revealed kernel >=30us => next target;
// (b) all <28us => gaps/launch overhead dominate => next round fuses
// kernels. absmax must stay exactly 9.766e-4 (exact node partition).
// ---------------------------------------------------------------------------

#define BSHIFT 8
#define BSIZE 256            // nodes per bucket
#define NBUCKET 512          // max buckets (requires N <= 131072)
#define BCAP 9728            // bucket capacity: mean 8192 + 16 sigma

typedef _Float16 f16x8 __attribute__((ext_vector_type(8)));
typedef float    f32x4 __attribute__((ext_vector_type(4)));

// ---------------- CSR build (identical to R24) ----------------

__global__ __launch_bounds__(512) void k_z512(int* __restrict__ gcnt) {
    gcnt[threadIdx.x] = 0;
}

__global__ __launch_bounds__(1024) void k_scatter1(const int* __restrict__ ei,
                                                   const float* __restrict__ ea,
                                                   int* __restrict__ gcnt,
                                                   int2* __restrict__ binned,
                                                   int E, int E4) {
    __shared__ int cnt[NBUCKET];
    __shared__ int cur[NBUCKET];
    int t = threadIdx.x, bl = blockIdx.x;
    if (t < NBUCKET) cnt[t] = 0;
    __syncthreads();

    int4 c0, c1, c2, c3;
    bool v0, v1, v2, v3;
    {
        int idx0 = bl * 4096 + t;
        int idx1 = idx0 + 1024, idx2 = idx0 + 2048, idx3 = idx0 + 3072;
        v0 = idx0 < E4; v1 = idx1 < E4; v2 = idx2 < E4; v3 = idx3 < E4;
        const int4* colv = (const int4*)(ei + E);
        if (v0) { c0 = colv[idx0];
            atomicAdd(&cnt[c0.x >> BSHIFT], 1); atomicAdd(&cnt[c0.y >> BSHIFT], 1);
            atomicAdd(&cnt[c0.z >> BSHIFT], 1); atomicAdd(&cnt[c0.w >> BSHIFT], 1); }
        if (v1) { c1 = colv[idx1];
            atomicAdd(&cnt[c1.x >> BSHIFT], 1); atomicAdd(&cnt[c1.y >> BSHIFT], 1);
            atomicAdd(&cnt[c1.z >> BSHIFT], 1); atomicAdd(&cnt[c1.w >> BSHIFT], 1); }
        if (v2) { c2 = colv[idx2];
            atomicAdd(&cnt[c2.x >> BSHIFT], 1); atomicAdd(&cnt[c2.y >> BSHIFT], 1);
            atomicAdd(&cnt[c2.z >> BSHIFT], 1); atomicAdd(&cnt[c2.w >> BSHIFT], 1); }
        if (v3) { c3 = colv[idx3];
            atomicAdd(&cnt[c3.x >> BSHIFT], 1); atomicAdd(&cnt[c3.y >> BSHIFT], 1);
            atomicAdd(&cnt[c3.z >> BSHIFT], 1); atomicAdd(&cnt[c3.w >> BSHIFT], 1); }
    }
    __syncthreads();
    if (t < NBUCKET) cur[t] = t * BCAP + atomicAdd(&gcnt[t], cnt[t]);
    __syncthreads();

#define SCAT_ONE(cc, rr, ww)                                                  \
    {                                                                         \
        int p = atomicAdd(&cur[(cc) >> BSHIFT], 1);                           \
        binned[p] = make_int2((((cc) & (BSIZE - 1)) << 17) | (rr),            \
                              __float_as_int(ww));                            \
    }
#define SCAT_QUAD(cq, idx)                                                    \
    {                                                                         \
        int4   r = ((const int4*)ei)[idx];                                    \
        float4 w = ((const float4*)ea)[idx];                                  \
        SCAT_ONE(cq.x, r.x, w.x); SCAT_ONE(cq.y, r.y, w.y);                   \
        SCAT_ONE(cq.z, r.z, w.z); SCAT_ONE(cq.w, r.w, w.w);                   \
    }
    {
        int idx0 = bl * 4096 + t;
        if (v0) SCAT_QUAD(c0, idx0);
        if (v1) SCAT_QUAD(c1, idx0 + 1024);
        if (v2) SCAT_QUAD(c2, idx0 + 2048);
        if (v3) SCAT_QUAD(c3, idx0 + 3072);
    }
#undef SCAT_QUAD
#undef SCAT_ONE
}

__global__ __launch_bounds__(1024) void k_finalize(const int2* __restrict__ binned,
                                                   const int* __restrict__ gcnt,
                                                   unsigned* __restrict__ csr,
                                                   int* __restrict__ offset,
                                                   float* __restrict__ dinv,
                                                   int N, int E) {
    __shared__ int   cnt[BSIZE];
    __shared__ float fsum[BSIZE];
    __shared__ int   inc[2][BSIZE];
    __shared__ int   cur[BSIZE];
    __shared__ int   sG[2][NBUCKET];
    int b = blockIdx.x, t = threadIdx.x;
    int ne = gcnt[b];
    int e0 = b * BCAP;

    if (t < NBUCKET) sG[0][t] = gcnt[t];
    if (t < BSIZE) { cnt[t] = 0; fsum[t] = 0.f; }
    __syncthreads();
    int src = 0;
    for (int off = 1; off < NBUCKET; off <<= 1) {
        if (t < NBUCKET)
            sG[1 - src][t] = sG[src][t] + ((t >= off) ? sG[src][t - off] : 0);
        src ^= 1;
        __syncthreads();
    }
    int c0 = (b > 0) ? sG[src][b - 1] : 0;   // csr base for this bucket

    for (int i = t; i < ne; i += 1024) {
        int2 ed = binned[e0 + i];
        unsigned cl = ((unsigned)ed.x) >> 17;
        atomicAdd(&cnt[cl], 1);
        atomicAdd(&fsum[cl], __int_as_float(ed.y));
    }
    __syncthreads();

    if (t < BSIZE) inc[0][t] = cnt[t];
    __syncthreads();
    src = 0;
    for (int off = 1; off < BSIZE; off <<= 1) {
        if (t < BSIZE)
            inc[1 - src][t] = inc[src][t] + ((t >= off) ? inc[src][t - off] : 0);
        src ^= 1;
        __syncthreads();
    }
    int nodeBase = b << BSHIFT;
    if (t < BSIZE) {
        int ex = (t > 0) ? inc[src][t - 1] : 0;
        cur[t] = c0 + ex;
        int node = nodeBase + t;
        if (node < N) {
            offset[node] = c0 + ex;
            dinv[node]   = rsqrtf(1.0f + fsum[t]);
        }
    }
    if (b == 0 && t == 0) offset[N] = E;
    __syncthreads();

    for (int i = t; i < ne; i += 1024) {
        int2 ed = binned[e0 + i];
        unsigned cl = ((unsigned)ed.x) >> 17;
        unsigned row = ((unsigned)ed.x) & 0x1FFFF;
        unsigned hb = (unsigned)__half_as_ushort(__float2half_rn(__int_as_float(ed.y))) & 0x7FFFu;
        int p = atomicAdd(&cur[cl], 1);
        csr[p] = (hb << 17) | row;
    }
}

// ---------------- dense compute (identical to R24) ----------------

__global__ __launch_bounds__(256) void k_gemm_mfma(const float* __restrict__ x,
                                                   const float* __restrict__ W1,
                                                   const float* __restrict__ dinv,
                                                   __half* __restrict__ hs, int n) {
    __shared__ _Float16 xh[64][136];
    __shared__ _Float16 wTh[64][136];
    int t = threadIdx.x;
    int nodeBase = blockIdx.x * 64;

    for (int i = t; i < 2048; i += 256) {
        int r = i >> 5, c4 = i & 31;
        int node = nodeBase + r;
        float4 v = make_float4(0.f, 0.f, 0.f, 0.f);
        if (node < n) v = ((const float4*)x)[node * 32 + c4];
        _Float16* dst = &xh[r][c4 * 4];
        dst[0] = (_Float16)v.x; dst[1] = (_Float16)v.y;
        dst[2] = (_Float16)v.z; dst[3] = (_Float16)v.w;
    }
    for (int i = t; i < 2048; i += 256) {
        int k = i >> 4, c4 = i & 15;
        float4 v = ((const float4*)W1)[k * 16 + c4];
        wTh[c4 * 4 + 0][k] = (_Float16)v.x;
        wTh[c4 * 4 + 1][k] = (_Float16)v.y;
        wTh[c4 * 4 + 2][k] = (_Float16)v.z;
        wTh[c4 * 4 + 3][k] = (_Float16)v.w;
    }
    __syncthreads();

    int w = t >> 6, lane = t & 63;
    int m = lane & 15, quad = lane >> 4;

    f32x4 acc[4] = {{0.f,0.f,0.f,0.f},{0.f,0.f,0.f,0.f},
                    {0.f,0.f,0.f,0.f},{0.f,0.f,0.f,0.f}};
#pragma unroll
    for (int ks = 0; ks < 128; ks += 32) {
        f16x8 a = *(const f16x8*)&xh[w * 16 + m][ks + quad * 8];
#pragma unroll
        for (int ct = 0; ct < 4; ++ct) {
            f16x8 bfr = *(const f16x8*)&wTh[ct * 16 + m][ks + quad * 8];
            acc[ct] = __builtin_amdgcn_mfma_f32_16x16x32_f16(a, bfr, acc[ct], 0, 0, 0);
        }
    }

#pragma unroll
    for (int reg = 0; reg < 4; ++reg) {
        int node = nodeBase + w * 16 + quad * 4 + reg;
        if (node < n) {
            float dv = dinv[node];
#pragma unroll
            for (int ct = 0; ct < 4; ++ct) {
                float v = acc[ct][reg] * dv;
                hs[(size_t)node * 64 + ct * 16 + m] = __float2half_rn(v);
            }
        }
    }
}

// ---------------- DPP reduce helpers (hardware-verified in R16) ----------

__device__ __forceinline__ float dpp_ror8(float x) {
    return __int_as_float(__builtin_amdgcn_update_dpp(
        0, __float_as_int(x), 0x128, 0xF, 0xF, true));
}
template<int CTRL>
__device__ __forceinline__ float dpp_mov(float x) {
    return __int_as_float(__builtin_amdgcn_update_dpp(
        0, __float_as_int(x), CTRL, 0xF, 0xF, true));
}
__device__ __forceinline__ float swz_xor16(float x) {
    return __int_as_float(__builtin_amdgcn_ds_swizzle(__float_as_int(x), 0x401F));
}

// ---------------- agg1 body (frozen R16 form), node range [n0, n1) --------

__device__ __forceinline__ void agg1_body(const __half* __restrict__ hs,
                                          const int* __restrict__ offset,
                                          const unsigned* __restrict__ csr,
                                          const float* __restrict__ dinv,
                                          const float* __restrict__ b1,
                                          const float* __restrict__ W2,
                                          float* __restrict__ h2s,
                                          int n0, int n1) {
    int wid  = __builtin_amdgcn_readfirstlane(
                   n0 + (int)((blockIdx.x * blockDim.x + threadIdx.x) >> 6));
    int lane = threadIdx.x & 63;
    if (wid >= n1) return;
    int off0 = __builtin_amdgcn_readfirstlane(offset[wid]);
    int off1 = __builtin_amdgcn_readfirstlane(offset[wid + 1]);
    int g = lane >> 3, s = lane & 7;
    unsigned sbyte = (unsigned)s << 4;          // s * 16 bytes
    const char* hsB = (const char*)hs;

    float acc[8] = {0.f, 0.f, 0.f, 0.f, 0.f, 0.f, 0.f, 0.f};

    {   // self loop (weight 1)
        f16x8 v = *(const f16x8*)(hsB + (((unsigned)wid) << 7) + sbyte);
        if (g == 0) {
#pragma unroll
            for (int k = 0; k < 8; ++k) acc[k] += (float)v[k];
        }
    }

    for (int j = off0; j < off1; j += 32) {
        int   i0 = j + g,      i1 = j + 8 + g,  i2 = j + 16 + g, i3 = j + 24 + g;
        bool  k0 = i0 < off1,  k1 = i1 < off1,  k2 = i2 < off1,  k3 = i3 < off1;
        unsigned eA = csr[k0 ? i0 : off1 - 1];
        unsigned eB = csr[k1 ? i1 : off1 - 1];
        unsigned eC = csr[k2 ? i2 : off1 - 1];
        unsigned eD = csr[k3 ? i3 : off1 - 1];
        f16x8 vA = *(const f16x8*)(hsB + ((eA & 0x1FFFFu) << 7) + sbyte);
        f16x8 vB = *(const f16x8*)(hsB + ((eB & 0x1FFFFu) << 7) + sbyte);
        f16x8 vC = *(const f16x8*)(hsB + ((eC & 0x1FFFFu) << 7) + sbyte);
        f16x8 vD = *(const f16x8*)(hsB + ((eD & 0x1FFFFu) << 7) + sbyte);
        float wA = k0 ? (float)__ushort_as_half((unsigned short)(eA >> 17)) : 0.f;
        float wB = k1 ? (float)__ushort_as_half((unsigned short)(eB >> 17)) : 0.f;
        float wC = k2 ? (float)__ushort_as_half((unsigned short)(eC >> 17)) : 0.f;
        float wD = k3 ? (float)__ushort_as_half((unsigned short)(eD >> 17)) : 0.f;
#pragma unroll
        for (int k = 0; k < 8; ++k) {
            acc[k] += wA * (float)vA[k];
            acc[k] += wB * (float)vB[k];
            acc[k] += wC * (float)vC[k];
            acc[k] += wD * (float)vD[k];
        }
    }

    // reduce over groups (lane bits 3,4,5): DPP ror8 + swizzle xor16 + shfl32
#pragma unroll
    for (int k = 0; k < 8; ++k) {
        float t = acc[k];
        t += dpp_ror8(t);
        t += swz_xor16(t);
        t += __shfl_xor(t, 32);
        acc[k] = t;
    }

    float di = dinv[wid];
    float4 bA = ((const float4*)b1)[s * 2], bB = ((const float4*)b1)[s * 2 + 1];
    float4 wA = ((const float4*)W2)[s * 2], wB = ((const float4*)W2)[s * 2 + 1];
    float p = 0.f;
    p += fmaxf(di * acc[0] + bA.x, 0.f) * wA.x;
    p += fmaxf(di * acc[1] + bA.y, 0.f) * wA.y;
    p += fmaxf(di * acc[2] + bA.z, 0.f) * wA.z;
    p += fmaxf(di * acc[3] + bA.w, 0.f) * wA.w;
    p += fmaxf(di * acc[4] + bB.x, 0.f) * wB.x;
    p += fmaxf(di * acc[5] + bB.y, 0.f) * wB.y;
    p += fmaxf(di * acc[6] + bB.z, 0.f) * wB.z;
    p += fmaxf(di * acc[7] + bB.w, 0.f) * wB.w;
    // reduce over s (lane bits 0,1,2): pure DPP
    p += dpp_mov<0xB1>(p);    // quad_perm [1,0,3,2] == xor 1
    p += dpp_mov<0x4E>(p);    // quad_perm [2,3,0,1] == xor 2
    p += dpp_mov<0x141>(p);   // row_half_mirror == xor 4 after 1,2 reduced
    if (lane == 0) h2s[wid] = di * p;
}

__global__ __launch_bounds__(256) void k_agg1_lo(const __half* __restrict__ hs,
                                                 const int* __restrict__ offset,
                                                 const unsigned* __restrict__ csr,
                                                 const float* __restrict__ dinv,
                                                 const float* __restrict__ b1,
                                                 const float* __restrict__ W2,
                                                 float* __restrict__ h2s,
                                                 int n0, int n1) {
    agg1_body(hs, offset, csr, dinv, b1, W2, h2s, n0, n1);
}

__global__ __launch_bounds__(256) void k_agg1_hi(const __half* __restrict__ hs,
                                                 const int* __restrict__ offset,
                                                 const unsigned* __restrict__ csr,
                                                 const float* __restrict__ dinv,
                                                 const float* __restrict__ b1,
                                                 const float* __restrict__ W2,
                                                 float* __restrict__ h2s,
                                                 int n0, int n1) {
    agg1_body(hs, offset, csr, dinv, b1, W2, h2s, n0, n1);
}

// ---------------- agg2 (identical to R24) ----------------

__global__ __launch_bounds__(256) void k_agg2(const float* __restrict__ h2s,
                                              const int* __restrict__ offset,
                                              const unsigned* __restrict__ csr,
                                              const float* __restrict__ dinv,
                                              const float* __restrict__ b2,
                                              float* __restrict__ out, int n) {
    int wid = __builtin_amdgcn_readfirstlane((int)((blockIdx.x * blockDim.x + threadIdx.x) >> 6));
    int lane = threadIdx.x & 63;
    if (wid >= n) return;
    int off0 = __builtin_amdgcn_readfirstlane(offset[wid]);
    int off1 = __builtin_amdgcn_readfirstlane(offset[wid + 1]);
    float di = dinv[wid];
    float p = 0.f;
    for (int e = off0 + lane; e < off1; e += 64) {
        unsigned ed = csr[e];
        p += (float)__ushort_as_half((unsigned short)(ed >> 17)) * h2s[ed & 0x1FFFF];
    }
#pragma unroll
    for (int s = 32; s > 0; s >>= 1) p += __shfl_xor(p, s);
    if (lane == 0) out[wid] = di * (p + h2s[wid]) + b2[0];
}

extern "C" void kernel_launch(void* const* d_in, const int* in_sizes, int n_in,
                              void* d_out, int out_size, void* d_ws, size_t ws_size,
                              hipStream_t stream) {
    const float* x  = (const float*)d_in[0];
    const int*   ei = (const int*)  d_in[1];
    const float* ea = (const float*)d_in[2];
    const float* W1 = (const float*)d_in[3];
    const float* b1 = (const float*)d_in[4];
    const float* W2 = (const float*)d_in[5];
    const float* b2 = (const float*)d_in[6];
    float* out = (float*)d_out;

    const int N  = in_sizes[0] / 128;   // 100000 (must be <= 131072)
    const int E  = in_sizes[2];         // 3200000
    const int E4 = E / 4;
    const int nbl  = (E4 + 4095) / 4096;        // 16384-edge chunks (196)
    const int nbkt = (N + BSIZE - 1) / BSIZE;   // active buckets (391)

    char* p = (char*)d_ws;
    auto alloc = [&](size_t bytes) -> void* {
        void* r = (void*)p;
        p += (bytes + 255) & ~(size_t)255;
        return r;
    };
    int*       gcnt   = (int*)      alloc((size_t)NBUCKET * 4);
    int2*      binned = (int2*)     alloc((size_t)NBUCKET * BCAP * 8);  // 39.8MB
    unsigned*  csr    = (unsigned*) alloc((size_t)E * 4);
    int*       offset = (int*)      alloc((size_t)(N + 1) * 4);
    float*     dinv   = (float*)    alloc((size_t)N * 4);
    __half*    hs     = (__half*)   alloc((size_t)N * 64 * 2);
    float*     h2s    = (float*)    alloc((size_t)N * 4);

    const int nb_gemm = (N + 63) / 64;
    const int Nh = N / 2;                         // 50000
    const int nb_lo = (Nh * 64 + 255) / 256;
    const int nb_hi = ((N - Nh) * 64 + 255) / 256;
    const int nb_wave = (N * 64 + 255) / 256;

    k_z512<<<1, 512, 0, stream>>>(gcnt);
    k_scatter1<<<nbl, 1024, 0, stream>>>(ei, ea, gcnt, binned, E, E4);
    k_finalize<<<nbkt, 1024, 0, stream>>>(binned, gcnt, csr, offset, dinv, N, E);
    k_gemm_mfma<<<nb_gemm, 256, 0, stream>>>(x, W1, dinv, hs, N);
    k_agg1_lo<<<nb_lo, 256, 0, stream>>>(hs, offset, csr, dinv, b1, W2, h2s, 0, Nh);
    k_agg1_hi<<<nb_hi, 256, 0, stream>>>(hs, offset, csr, dinv, b1, W2, h2s, Nh, N);
    k_agg2<<<nb_wave, 256, 0, stream>>>(h2s, offset, csr, dinv, b2, out, N);
}

// Round 12
// 282.084 us; speedup vs baseline: 1.0029x; 1.0029x over previous
//
#include <hip/hip_runtime.h>
#include <hip/hip_fp16.h>

// ---------------------------------------------------------------------------
// GCN 2-layer (PyG GCNConv) on MI355X — R27.
// R26 diagnostic: k_scatter1 unmasked at ~45us, VALU 1.6%, occ 15-20%,
// WRITE 38MB (1.45x amp from unaligned 256B bucket runs). 196 blocks =
// 3136 waves -> R17 latency-starvation signature inside the build.
// R27 single change-unit (+ revert diagnostic split):
//   - k_scatter1: 16384 -> 8192-edge chunks (2 int4/thread, grid 391):
//     every CU gets a block, 2x waves. Cost: runs 32 -> 16 edges (128B) ->
//     write amp ~1.45 -> ~1.6 (+4MB), bought deliberately: latency >> traffic
//     at VALU 1.6%. Reservation atomics 100K -> 200K (391/address, spread).
//   - agg1 re-merged to single frozen R16 kernel (split cost ~2us, info
//     banked: scatter1 was the hidden mass).
// Predict: scatter1 ~28-32us (occ ~35-40%), total 282.9 -> ~262-268us,
// agg1 back to ~52 top-5 monopoly, absmax 9.766e-4.
// Failure: (a) scatter1 flat => store/atomic-serialization-bound => in-LDS
// counting sort + coalesced run emission next; (b) total flat => launch
// gaps => fuse z512+scatter1, finalize+gemm.
// ---------------------------------------------------------------------------

#define BSHIFT 8
#define BSIZE 256            // nodes per bucket
#define NBUCKET 512          // max buckets (requires N <= 131072)
#define BCAP 9728            // bucket capacity: mean 8192 + 16 sigma

typedef _Float16 f16x8 __attribute__((ext_vector_type(8)));
typedef float    f32x4 __attribute__((ext_vector_type(4)));

// ---------------- CSR build ----------------

__global__ __launch_bounds__(512) void k_z512(int* __restrict__ gcnt) {
    gcnt[threadIdx.x] = 0;
}

// 8192 edges per block (2 int4/thread), grid 391: LDS bucket count ->
// global reservation -> scatter into fixed bucket segments.
__global__ __launch_bounds__(1024) void k_scatter1(const int* __restrict__ ei,
                                                   const float* __restrict__ ea,
                                                   int* __restrict__ gcnt,
                                                   int2* __restrict__ binned,
                                                   int E, int E4) {
    __shared__ int cnt[NBUCKET];
    __shared__ int cur[NBUCKET];
    int t = threadIdx.x, bl = blockIdx.x;
    if (t < NBUCKET) cnt[t] = 0;
    __syncthreads();

    int4 c0, c1;
    bool v0, v1;
    {
        int idx0 = bl * 2048 + t;
        int idx1 = idx0 + 1024;
        v0 = idx0 < E4; v1 = idx1 < E4;
        const int4* colv = (const int4*)(ei + E);
        if (v0) { c0 = colv[idx0];
            atomicAdd(&cnt[c0.x >> BSHIFT], 1); atomicAdd(&cnt[c0.y >> BSHIFT], 1);
            atomicAdd(&cnt[c0.z >> BSHIFT], 1); atomicAdd(&cnt[c0.w >> BSHIFT], 1); }
        if (v1) { c1 = colv[idx1];
            atomicAdd(&cnt[c1.x >> BSHIFT], 1); atomicAdd(&cnt[c1.y >> BSHIFT], 1);
            atomicAdd(&cnt[c1.z >> BSHIFT], 1); atomicAdd(&cnt[c1.w >> BSHIFT], 1); }
    }
    __syncthreads();
    if (t < NBUCKET) cur[t] = t * BCAP + atomicAdd(&gcnt[t], cnt[t]);
    __syncthreads();

#define SCAT_ONE(cc, rr, ww)                                                  \
    {                                                                         \
        int p = atomicAdd(&cur[(cc) >> BSHIFT], 1);                           \
        binned[p] = make_int2((((cc) & (BSIZE - 1)) << 17) | (rr),            \
                              __float_as_int(ww));                            \
    }
#define SCAT_QUAD(cq, idx)                                                    \
    {                                                                         \
        int4   r = ((const int4*)ei)[idx];                                    \
        float4 w = ((const float4*)ea)[idx];                                  \
        SCAT_ONE(cq.x, r.x, w.x); SCAT_ONE(cq.y, r.y, w.y);                   \
        SCAT_ONE(cq.z, r.z, w.z); SCAT_ONE(cq.w, r.w, w.w);                   \
    }
    {
        int idx0 = bl * 2048 + t;
        if (v0) SCAT_QUAD(c0, idx0);
        if (v1) SCAT_QUAD(c1, idx0 + 1024);
    }
#undef SCAT_QUAD
#undef SCAT_ONE
}

// finalize (identical to R24): 391 blocks, ~9KB LDS, inline 512-wide scan.
__global__ __launch_bounds__(1024) void k_finalize(const int2* __restrict__ binned,
                                                   const int* __restrict__ gcnt,
                                                   unsigned* __restrict__ csr,
                                                   int* __restrict__ offset,
                                                   float* __restrict__ dinv,
                                                   int N, int E) {
    __shared__ int   cnt[BSIZE];
    __shared__ float fsum[BSIZE];
    __shared__ int   inc[2][BSIZE];
    __shared__ int   cur[BSIZE];
    __shared__ int   sG[2][NBUCKET];
    int b = blockIdx.x, t = threadIdx.x;
    int ne = gcnt[b];
    int e0 = b * BCAP;

    if (t < NBUCKET) sG[0][t] = gcnt[t];
    if (t < BSIZE) { cnt[t] = 0; fsum[t] = 0.f; }
    __syncthreads();
    int src = 0;
    for (int off = 1; off < NBUCKET; off <<= 1) {
        if (t < NBUCKET)
            sG[1 - src][t] = sG[src][t] + ((t >= off) ? sG[src][t - off] : 0);
        src ^= 1;
        __syncthreads();
    }
    int c0 = (b > 0) ? sG[src][b - 1] : 0;   // csr base for this bucket

    for (int i = t; i < ne; i += 1024) {
        int2 ed = binned[e0 + i];
        unsigned cl = ((unsigned)ed.x) >> 17;
        atomicAdd(&cnt[cl], 1);
        atomicAdd(&fsum[cl], __int_as_float(ed.y));
    }
    __syncthreads();

    if (t < BSIZE) inc[0][t] = cnt[t];
    __syncthreads();
    src = 0;
    for (int off = 1; off < BSIZE; off <<= 1) {
        if (t < BSIZE)
            inc[1 - src][t] = inc[src][t] + ((t >= off) ? inc[src][t - off] : 0);
        src ^= 1;
        __syncthreads();
    }
    int nodeBase = b << BSHIFT;
    if (t < BSIZE) {
        int ex = (t > 0) ? inc[src][t - 1] : 0;
        cur[t] = c0 + ex;
        int node = nodeBase + t;
        if (node < N) {
            offset[node] = c0 + ex;
            dinv[node]   = rsqrtf(1.0f + fsum[t]);
        }
    }
    if (b == 0 && t == 0) offset[N] = E;
    __syncthreads();

    for (int i = t; i < ne; i += 1024) {
        int2 ed = binned[e0 + i];
        unsigned cl = ((unsigned)ed.x) >> 17;
        unsigned row = ((unsigned)ed.x) & 0x1FFFF;
        unsigned hb = (unsigned)__half_as_ushort(__float2half_rn(__int_as_float(ed.y))) & 0x7FFFu;
        int p = atomicAdd(&cur[cl], 1);
        csr[p] = (hb << 17) | row;
    }
}

// ---------------- dense compute (identical to R24) ----------------

__global__ __launch_bounds__(256) void k_gemm_mfma(const float* __restrict__ x,
                                                   const float* __restrict__ W1,
                                                   const float* __restrict__ dinv,
                                                   __half* __restrict__ hs, int n) {
    __shared__ _Float16 xh[64][136];
    __shared__ _Float16 wTh[64][136];
    int t = threadIdx.x;
    int nodeBase = blockIdx.x * 64;

    for (int i = t; i < 2048; i += 256) {
        int r = i >> 5, c4 = i & 31;
        int node = nodeBase + r;
        float4 v = make_float4(0.f, 0.f, 0.f, 0.f);
        if (node < n) v = ((const float4*)x)[node * 32 + c4];
        _Float16* dst = &xh[r][c4 * 4];
        dst[0] = (_Float16)v.x; dst[1] = (_Float16)v.y;
        dst[2] = (_Float16)v.z; dst[3] = (_Float16)v.w;
    }
    for (int i = t; i < 2048; i += 256) {
        int k = i >> 4, c4 = i & 15;
        float4 v = ((const float4*)W1)[k * 16 + c4];
        wTh[c4 * 4 + 0][k] = (_Float16)v.x;
        wTh[c4 * 4 + 1][k] = (_Float16)v.y;
        wTh[c4 * 4 + 2][k] = (_Float16)v.z;
        wTh[c4 * 4 + 3][k] = (_Float16)v.w;
    }
    __syncthreads();

    int w = t >> 6, lane = t & 63;
    int m = lane & 15, quad = lane >> 4;

    f32x4 acc[4] = {{0.f,0.f,0.f,0.f},{0.f,0.f,0.f,0.f},
                    {0.f,0.f,0.f,0.f},{0.f,0.f,0.f,0.f}};
#pragma unroll
    for (int ks = 0; ks < 128; ks += 32) {
        f16x8 a = *(const f16x8*)&xh[w * 16 + m][ks + quad * 8];
#pragma unroll
        for (int ct = 0; ct < 4; ++ct) {
            f16x8 bfr = *(const f16x8*)&wTh[ct * 16 + m][ks + quad * 8];
            acc[ct] = __builtin_amdgcn_mfma_f32_16x16x32_f16(a, bfr, acc[ct], 0, 0, 0);
        }
    }

#pragma unroll
    for (int reg = 0; reg < 4; ++reg) {
        int node = nodeBase + w * 16 + quad * 4 + reg;
        if (node < n) {
            float dv = dinv[node];
#pragma unroll
            for (int ct = 0; ct < 4; ++ct) {
                float v = acc[ct][reg] * dv;
                hs[(size_t)node * 64 + ct * 16 + m] = __float2half_rn(v);
            }
        }
    }
}

// ---------------- DPP reduce helpers (hardware-verified in R16) ----------

__device__ __forceinline__ float dpp_ror8(float x) {
    return __int_as_float(__builtin_amdgcn_update_dpp(
        0, __float_as_int(x), 0x128, 0xF, 0xF, true));
}
template<int CTRL>
__device__ __forceinline__ float dpp_mov(float x) {
    return __int_as_float(__builtin_amdgcn_update_dpp(
        0, __float_as_int(x), CTRL, 0xF, 0xF, true));
}
__device__ __forceinline__ float swz_xor16(float x) {
    return __int_as_float(__builtin_amdgcn_ds_swizzle(__float_as_int(x), 0x401F));
}

// ---------------- agg1 (frozen R16 form, re-merged) ----------------

__global__ __launch_bounds__(256) void k_agg1(const __half* __restrict__ hs,
                                              const int* __restrict__ offset,
                                              const unsigned* __restrict__ csr,
                                              const float* __restrict__ dinv,
                                              const float* __restrict__ b1,
                                              const float* __restrict__ W2,
                                              float* __restrict__ h2s, int n) {
    int wid  = __builtin_amdgcn_readfirstlane(
                   (int)((blockIdx.x * blockDim.x + threadIdx.x) >> 6));
    int lane = threadIdx.x & 63;
    if (wid >= n) return;
    int off0 = __builtin_amdgcn_readfirstlane(offset[wid]);
    int off1 = __builtin_amdgcn_readfirstlane(offset[wid + 1]);
    int g = lane >> 3, s = lane & 7;
    unsigned sbyte = (unsigned)s << 4;          // s * 16 bytes
    const char* hsB = (const char*)hs;

    float acc[8] = {0.f, 0.f, 0.f, 0.f, 0.f, 0.f, 0.f, 0.f};

    {   // self loop (weight 1)
        f16x8 v = *(const f16x8*)(hsB + (((unsigned)wid) << 7) + sbyte);
        if (g == 0) {
#pragma unroll
            for (int k = 0; k < 8; ++k) acc[k] += (float)v[k];
        }
    }

    for (int j = off0; j < off1; j += 32) {
        int   i0 = j + g,      i1 = j + 8 + g,  i2 = j + 16 + g, i3 = j + 24 + g;
        bool  k0 = i0 < off1,  k1 = i1 < off1,  k2 = i2 < off1,  k3 = i3 < off1;
        unsigned eA = csr[k0 ? i0 : off1 - 1];
        unsigned eB = csr[k1 ? i1 : off1 - 1];
        unsigned eC = csr[k2 ? i2 : off1 - 1];
        unsigned eD = csr[k3 ? i3 : off1 - 1];
        f16x8 vA = *(const f16x8*)(hsB + ((eA & 0x1FFFFu) << 7) + sbyte);
        f16x8 vB = *(const f16x8*)(hsB + ((eB & 0x1FFFFu) << 7) + sbyte);
        f16x8 vC = *(const f16x8*)(hsB + ((eC & 0x1FFFFu) << 7) + sbyte);
        f16x8 vD = *(const f16x8*)(hsB + ((eD & 0x1FFFFu) << 7) + sbyte);
        float wA = k0 ? (float)__ushort_as_half((unsigned short)(eA >> 17)) : 0.f;
        float wB = k1 ? (float)__ushort_as_half((unsigned short)(eB >> 17)) : 0.f;
        float wC = k2 ? (float)__ushort_as_half((unsigned short)(eC >> 17)) : 0.f;
        float wD = k3 ? (float)__ushort_as_half((unsigned short)(eD >> 17)) : 0.f;
#pragma unroll
        for (int k = 0; k < 8; ++k) {
            acc[k] += wA * (float)vA[k];
            acc[k] += wB * (float)vB[k];
            acc[k] += wC * (float)vC[k];
            acc[k] += wD * (float)vD[k];
        }
    }

    // reduce over groups (lane bits 3,4,5): DPP ror8 + swizzle xor16 + shfl32
#pragma unroll
    for (int k = 0; k < 8; ++k) {
        float t = acc[k];
        t += dpp_ror8(t);
        t += swz_xor16(t);
        t += __shfl_xor(t, 32);
        acc[k] = t;
    }

    float di = dinv[wid];
    float4 bA = ((const float4*)b1)[s * 2], bB = ((const float4*)b1)[s * 2 + 1];
    float4 wA = ((const float4*)W2)[s * 2], wB = ((const float4*)W2)[s * 2 + 1];
    float p = 0.f;
    p += fmaxf(di * acc[0] + bA.x, 0.f) * wA.x;
    p += fmaxf(di * acc[1] + bA.y, 0.f) * wA.y;
    p += fmaxf(di * acc[2] + bA.z, 0.f) * wA.z;
    p += fmaxf(di * acc[3] + bA.w, 0.f) * wA.w;
    p += fmaxf(di * acc[4] + bB.x, 0.f) * wB.x;
    p += fmaxf(di * acc[5] + bB.y, 0.f) * wB.y;
    p += fmaxf(di * acc[6] + bB.z, 0.f) * wB.z;
    p += fmaxf(di * acc[7] + bB.w, 0.f) * wB.w;
    // reduce over s (lane bits 0,1,2): pure DPP
    p += dpp_mov<0xB1>(p);    // quad_perm [1,0,3,2] == xor 1
    p += dpp_mov<0x4E>(p);    // quad_perm [2,3,0,1] == xor 2
    p += dpp_mov<0x141>(p);   // row_half_mirror == xor 4 after 1,2 reduced
    if (lane == 0) h2s[wid] = di * p;
}

// ---------------- agg2 (identical to R24) ----------------

__global__ __launch_bounds__(256) void k_agg2(const float* __restrict__ h2s,
                                              const int* __restrict__ offset,
                                              const unsigned* __restrict__ csr,
                                              const float* __restrict__ dinv,
                                              const float* __restrict__ b2,
                                              float* __restrict__ out, int n) {
    int wid = __builtin_amdgcn_readfirstlane((int)((blockIdx.x * blockDim.x + threadIdx.x) >> 6));
    int lane = threadIdx.x & 63;
    if (wid >= n) return;
    int off0 = __builtin_amdgcn_readfirstlane(offset[wid]);
    int off1 = __builtin_amdgcn_readfirstlane(offset[wid + 1]);
    float di = dinv[wid];
    float p = 0.f;
    for (int e = off0 + lane; e < off1; e += 64) {
        unsigned ed = csr[e];
        p += (float)__ushort_as_half((unsigned short)(ed >> 17)) * h2s[ed & 0x1FFFF];
    }
#pragma unroll
    for (int s = 32; s > 0; s >>= 1) p += __shfl_xor(p, s);
    if (lane == 0) out[wid] = di * (p + h2s[wid]) + b2[0];
}

extern "C" void kernel_launch(void* const* d_in, const int* in_sizes, int n_in,
                              void* d_out, int out_size, void* d_ws, size_t ws_size,
                              hipStream_t stream) {
    const float* x  = (const float*)d_in[0];
    const int*   ei = (const int*)  d_in[1];
    const float* ea = (const float*)d_in[2];
    const float* W1 = (const float*)d_in[3];
    const float* b1 = (const float*)d_in[4];
    const float* W2 = (const float*)d_in[5];
    const float* b2 = (const float*)d_in[6];
    float* out = (float*)d_out;

    const int N  = in_sizes[0] / 128;   // 100000 (must be <= 131072)
    const int E  = in_sizes[2];         // 3200000
    const int E4 = E / 4;
    const int nbl  = (E4 + 2047) / 2048;        // 8192-edge chunks (391)
    const int nbkt = (N + BSIZE - 1) / BSIZE;   // active buckets (391)

    char* p = (char*)d_ws;
    auto alloc = [&](size_t bytes) -> void* {
        void* r = (void*)p;
        p += (bytes + 255) & ~(size_t)255;
        return r;
    };
    int*       gcnt   = (int*)      alloc((size_t)NBUCKET * 4);
    int2*      binned = (int2*)     alloc((size_t)NBUCKET * BCAP * 8);  // 39.8MB
    unsigned*  csr    = (unsigned*) alloc((size_t)E * 4);
    int*       offset = (int*)      alloc((size_t)(N + 1) * 4);
    float*     dinv   = (float*)    alloc((size_t)N * 4);
    __half*    hs     = (__half*)   alloc((size_t)N * 64 * 2);
    float*     h2s    = (float*)    alloc((size_t)N * 4);

    const int nb_gemm = (N + 63) / 64;
    const int nb_wave = (N * 64 + 255) / 256;   // one 64-wide wave per node

    k_z512<<<1, 512, 0, stream>>>(gcnt);
    k_scatter1<<<nbl, 1024, 0, stream>>>(ei, ea, gcnt, binned, E, E4);
    k_finalize<<<nbkt, 1024, 0, stream>>>(binned, gcnt, csr, offset, dinv, N, E);
    k_gemm_mfma<<<nb_gemm, 256, 0, stream>>>(x, W1, dinv, hs, N);
    k_agg1<<<nb_wave, 256, 0, stream>>>(hs, offset, csr, dinv, b1, W2, h2s, N);
    k_agg2<<<nb_wave, 256, 0, stream>>>(h2s, offset, csr, dinv, b2, out, N);
}

// Round 13
// 269.919 us; speedup vs baseline: 1.0481x; 1.0451x over previous
//
#include <hip/hip_runtime.h>
#include <hip/hip_fp16.h>

// ---------------------------------------------------------------------------
// GCN 2-layer (PyG GCNConv) on MI355X — R28.
// R27 post-mortem: scatter1 TLP boost neutral (282.1 vs R24 280.9) ->
// pre-registered (a): scatter1 is STORE-SERIALIZATION bound — 64 lanes
// store 8B to 64 different bucket cursors -> nothing coalesces, 25.6M
// scattered line-touches, WRITE amp 1.45-1.6x.
// R28 change-unit: in-LDS counting sort + coalesced emission in k_scatter1.
//   stage[8192] (64KB) + sbk[8192] u16 (16KB): edges staged bucket-sorted
//   via LDS cursor atomics, then emitted with consecutive threads writing
//   consecutive global addresses (runs of ~16 edges = 128B lines) -> ~8x
//   fewer store transactions, WRITE 38 -> ~27MB. LDS 92KB -> 1 block/CU:
//   free, since R27 proved TLP is not scatter1's constraint.
// Also: agg1 kept SPLIT (lo/hi ~27us, ~2us cost) so the top-5 board can
// show scatter1's new time (3 flat rounds were board-blind behind agg1).
// finalize/gemm/agg2 byte-identical to R27.
// Predict: scatter1 ~22-28us, total ~263-270us, absmax 9.766e-4.
// Failure: (a) scatter1 >=40 => read-latency floor, pivot to finalize;
// (b) scatter1 drops, total flat => launch gaps => fuse kernels next.
// ---------------------------------------------------------------------------

#define BSHIFT 8
#define BSIZE 256            // nodes per bucket
#define NBUCKET 512          // max buckets (requires N <= 131072)
#define BCAP 9728            // bucket capacity: mean 8192 + 16 sigma

typedef _Float16 f16x8 __attribute__((ext_vector_type(8)));
typedef float    f32x4 __attribute__((ext_vector_type(4)));

// ---------------- CSR build ----------------

__global__ __launch_bounds__(512) void k_z512(int* __restrict__ gcnt) {
    gcnt[threadIdx.x] = 0;
}

// 8192 edges per block, 1024 threads. LDS count -> scan -> reservation ->
// bucket-sorted LDS staging -> coalesced emission.
__global__ __launch_bounds__(1024) void k_scatter1(const int* __restrict__ ei,
                                                   const float* __restrict__ ea,
                                                   int* __restrict__ gcnt,
                                                   int2* __restrict__ binned,
                                                   int E, int E4) {
    __shared__ int  cnt[NBUCKET];          // 2KB
    __shared__ int  lofs[NBUCKET];         // 2KB exclusive scan
    __shared__ int  gbase[NBUCKET];        // 2KB global run base
    __shared__ int  lcur[NBUCKET];         // 2KB staging cursor
    __shared__ int  sS[2][NBUCKET];        // 4KB scan temp
    __shared__ int2 stage[8192];           // 64KB payload, bucket-sorted
    __shared__ unsigned short sbk[8192];   // 16KB bucket id per slot

    int t = threadIdx.x, bl = blockIdx.x;
    if (t < NBUCKET) cnt[t] = 0;
    __syncthreads();

    int idx0 = bl * 2048 + t;
    int idx1 = idx0 + 1024;
    bool v0 = idx0 < E4, v1 = idx1 < E4;
    const int4* colv = (const int4*)(ei + E);
    int4 c0, c1;
    if (v0) { c0 = colv[idx0];
        atomicAdd(&cnt[c0.x >> BSHIFT], 1); atomicAdd(&cnt[c0.y >> BSHIFT], 1);
        atomicAdd(&cnt[c0.z >> BSHIFT], 1); atomicAdd(&cnt[c0.w >> BSHIFT], 1); }
    if (v1) { c1 = colv[idx1];
        atomicAdd(&cnt[c1.x >> BSHIFT], 1); atomicAdd(&cnt[c1.y >> BSHIFT], 1);
        atomicAdd(&cnt[c1.z >> BSHIFT], 1); atomicAdd(&cnt[c1.w >> BSHIFT], 1); }
    __syncthreads();

    // exclusive scan of cnt -> lofs; reservation -> gbase
    if (t < NBUCKET) sS[0][t] = cnt[t];
    __syncthreads();
    int src = 0;
    for (int off = 1; off < NBUCKET; off <<= 1) {
        if (t < NBUCKET)
            sS[1 - src][t] = sS[src][t] + ((t >= off) ? sS[src][t - off] : 0);
        src ^= 1;
        __syncthreads();
    }
    if (t < NBUCKET) {
        int ex = (t > 0) ? sS[src][t - 1] : 0;
        lofs[t] = ex;
        lcur[t] = ex;
        gbase[t] = t * BCAP + atomicAdd(&gcnt[t], cnt[t]);
    }
    __syncthreads();

#define STAGE_ONE(cc, rr, ww)                                                 \
    {                                                                         \
        int bk = (cc) >> BSHIFT;                                              \
        int p = atomicAdd(&lcur[bk], 1);                                      \
        stage[p] = make_int2((((cc) & (BSIZE - 1)) << 17) | (rr),             \
                             __float_as_int(ww));                             \
        sbk[p] = (unsigned short)bk;                                          \
    }
    {
        const int4*   rowv = (const int4*)ei;
        const float4* eav  = (const float4*)ea;
        if (v0) {
            int4 r = rowv[idx0]; float4 w = eav[idx0];
            STAGE_ONE(c0.x, r.x, w.x); STAGE_ONE(c0.y, r.y, w.y);
            STAGE_ONE(c0.z, r.z, w.z); STAGE_ONE(c0.w, r.w, w.w);
        }
        if (v1) {
            int4 r = rowv[idx1]; float4 w = eav[idx1];
            STAGE_ONE(c1.x, r.x, w.x); STAGE_ONE(c1.y, r.y, w.y);
            STAGE_ONE(c1.z, r.z, w.z); STAGE_ONE(c1.w, r.w, w.w);
        }
    }
#undef STAGE_ONE
    __syncthreads();

    // coalesced emission: consecutive threads -> consecutive global addrs
    int nI = E4 - bl * 2048;
    if (nI > 2048) nI = 2048;
    int ne_blk = nI * 4;
    for (int i = t; i < ne_blk; i += 1024) {
        int bk = sbk[i];
        binned[gbase[bk] + (i - lofs[bk])] = stage[i];
    }
}

// finalize (identical to R24/R27): 391 blocks, ~9KB LDS, inline 512 scan.
__global__ __launch_bounds__(1024) void k_finalize(const int2* __restrict__ binned,
                                                   const int* __restrict__ gcnt,
                                                   unsigned* __restrict__ csr,
                                                   int* __restrict__ offset,
                                                   float* __restrict__ dinv,
                                                   int N, int E) {
    __shared__ int   cnt[BSIZE];
    __shared__ float fsum[BSIZE];
    __shared__ int   inc[2][BSIZE];
    __shared__ int   cur[BSIZE];
    __shared__ int   sG[2][NBUCKET];
    int b = blockIdx.x, t = threadIdx.x;
    int ne = gcnt[b];
    int e0 = b * BCAP;

    if (t < NBUCKET) sG[0][t] = gcnt[t];
    if (t < BSIZE) { cnt[t] = 0; fsum[t] = 0.f; }
    __syncthreads();
    int src = 0;
    for (int off = 1; off < NBUCKET; off <<= 1) {
        if (t < NBUCKET)
            sG[1 - src][t] = sG[src][t] + ((t >= off) ? sG[src][t - off] : 0);
        src ^= 1;
        __syncthreads();
    }
    int c0 = (b > 0) ? sG[src][b - 1] : 0;   // csr base for this bucket

    for (int i = t; i < ne; i += 1024) {
        int2 ed = binned[e0 + i];
        unsigned cl = ((unsigned)ed.x) >> 17;
        atomicAdd(&cnt[cl], 1);
        atomicAdd(&fsum[cl], __int_as_float(ed.y));
    }
    __syncthreads();

    if (t < BSIZE) inc[0][t] = cnt[t];
    __syncthreads();
    src = 0;
    for (int off = 1; off < BSIZE; off <<= 1) {
        if (t < BSIZE)
            inc[1 - src][t] = inc[src][t] + ((t >= off) ? inc[src][t - off] : 0);
        src ^= 1;
        __syncthreads();
    }
    int nodeBase = b << BSHIFT;
    if (t < BSIZE) {
        int ex = (t > 0) ? inc[src][t - 1] : 0;
        cur[t] = c0 + ex;
        int node = nodeBase + t;
        if (node < N) {
            offset[node] = c0 + ex;
            dinv[node]   = rsqrtf(1.0f + fsum[t]);
        }
    }
    if (b == 0 && t == 0) offset[N] = E;
    __syncthreads();

    for (int i = t; i < ne; i += 1024) {
        int2 ed = binned[e0 + i];
        unsigned cl = ((unsigned)ed.x) >> 17;
        unsigned row = ((unsigned)ed.x) & 0x1FFFF;
        unsigned hb = (unsigned)__half_as_ushort(__float2half_rn(__int_as_float(ed.y))) & 0x7FFFu;
        int p = atomicAdd(&cur[cl], 1);
        csr[p] = (hb << 17) | row;
    }
}

// ---------------- dense compute (identical to R24) ----------------

__global__ __launch_bounds__(256) void k_gemm_mfma(const float* __restrict__ x,
                                                   const float* __restrict__ W1,
                                                   const float* __restrict__ dinv,
                                                   __half* __restrict__ hs, int n) {
    __shared__ _Float16 xh[64][136];
    __shared__ _Float16 wTh[64][136];
    int t = threadIdx.x;
    int nodeBase = blockIdx.x * 64;

    for (int i = t; i < 2048; i += 256) {
        int r = i >> 5, c4 = i & 31;
        int node = nodeBase + r;
        float4 v = make_float4(0.f, 0.f, 0.f, 0.f);
        if (node < n) v = ((const float4*)x)[node * 32 + c4];
        _Float16* dst = &xh[r][c4 * 4];
        dst[0] = (_Float16)v.x; dst[1] = (_Float16)v.y;
        dst[2] = (_Float16)v.z; dst[3] = (_Float16)v.w;
    }
    for (int i = t; i < 2048; i += 256) {
        int k = i >> 4, c4 = i & 15;
        float4 v = ((const float4*)W1)[k * 16 + c4];
        wTh[c4 * 4 + 0][k] = (_Float16)v.x;
        wTh[c4 * 4 + 1][k] = (_Float16)v.y;
        wTh[c4 * 4 + 2][k] = (_Float16)v.z;
        wTh[c4 * 4 + 3][k] = (_Float16)v.w;
    }
    __syncthreads();

    int w = t >> 6, lane = t & 63;
    int m = lane & 15, quad = lane >> 4;

    f32x4 acc[4] = {{0.f,0.f,0.f,0.f},{0.f,0.f,0.f,0.f},
                    {0.f,0.f,0.f,0.f},{0.f,0.f,0.f,0.f}};
#pragma unroll
    for (int ks = 0; ks < 128; ks += 32) {
        f16x8 a = *(const f16x8*)&xh[w * 16 + m][ks + quad * 8];
#pragma unroll
        for (int ct = 0; ct < 4; ++ct) {
            f16x8 bfr = *(const f16x8*)&wTh[ct * 16 + m][ks + quad * 8];
            acc[ct] = __builtin_amdgcn_mfma_f32_16x16x32_f16(a, bfr, acc[ct], 0, 0, 0);
        }
    }

#pragma unroll
    for (int reg = 0; reg < 4; ++reg) {
        int node = nodeBase + w * 16 + quad * 4 + reg;
        if (node < n) {
            float dv = dinv[node];
#pragma unroll
            for (int ct = 0; ct < 4; ++ct) {
                float v = acc[ct][reg] * dv;
                hs[(size_t)node * 64 + ct * 16 + m] = __float2half_rn(v);
            }
        }
    }
}

// ---------------- DPP reduce helpers (hardware-verified in R16) ----------

__device__ __forceinline__ float dpp_ror8(float x) {
    return __int_as_float(__builtin_amdgcn_update_dpp(
        0, __float_as_int(x), 0x128, 0xF, 0xF, true));
}
template<int CTRL>
__device__ __forceinline__ float dpp_mov(float x) {
    return __int_as_float(__builtin_amdgcn_update_dpp(
        0, __float_as_int(x), CTRL, 0xF, 0xF, true));
}
__device__ __forceinline__ float swz_xor16(float x) {
    return __int_as_float(__builtin_amdgcn_ds_swizzle(__float_as_int(x), 0x401F));
}

// ---------------- agg1 body (frozen R16 form), node range [n0, n1) --------

__device__ __forceinline__ void agg1_body(const __half* __restrict__ hs,
                                          const int* __restrict__ offset,
                                          const unsigned* __restrict__ csr,
                                          const float* __restrict__ dinv,
                                          const float* __restrict__ b1,
                                          const float* __restrict__ W2,
                                          float* __restrict__ h2s,
                                          int n0, int n1) {
    int wid  = __builtin_amdgcn_readfirstlane(
                   n0 + (int)((blockIdx.x * blockDim.x + threadIdx.x) >> 6));
    int lane = threadIdx.x & 63;
    if (wid >= n1) return;
    int off0 = __builtin_amdgcn_readfirstlane(offset[wid]);
    int off1 = __builtin_amdgcn_readfirstlane(offset[wid + 1]);
    int g = lane >> 3, s = lane & 7;
    unsigned sbyte = (unsigned)s << 4;          // s * 16 bytes
    const char* hsB = (const char*)hs;

    float acc[8] = {0.f, 0.f, 0.f, 0.f, 0.f, 0.f, 0.f, 0.f};

    {   // self loop (weight 1)
        f16x8 v = *(const f16x8*)(hsB + (((unsigned)wid) << 7) + sbyte);
        if (g == 0) {
#pragma unroll
            for (int k = 0; k < 8; ++k) acc[k] += (float)v[k];
        }
    }

    for (int j = off0; j < off1; j += 32) {
        int   i0 = j + g,      i1 = j + 8 + g,  i2 = j + 16 + g, i3 = j + 24 + g;
        bool  k0 = i0 < off1,  k1 = i1 < off1,  k2 = i2 < off1,  k3 = i3 < off1;
        unsigned eA = csr[k0 ? i0 : off1 - 1];
        unsigned eB = csr[k1 ? i1 : off1 - 1];
        unsigned eC = csr[k2 ? i2 : off1 - 1];
        unsigned eD = csr[k3 ? i3 : off1 - 1];
        f16x8 vA = *(const f16x8*)(hsB + ((eA & 0x1FFFFu) << 7) + sbyte);
        f16x8 vB = *(const f16x8*)(hsB + ((eB & 0x1FFFFu) << 7) + sbyte);
        f16x8 vC = *(const f16x8*)(hsB + ((eC & 0x1FFFFu) << 7) + sbyte);
        f16x8 vD = *(const f16x8*)(hsB + ((eD & 0x1FFFFu) << 7) + sbyte);
        float wA = k0 ? (float)__ushort_as_half((unsigned short)(eA >> 17)) : 0.f;
        float wB = k1 ? (float)__ushort_as_half((unsigned short)(eB >> 17)) : 0.f;
        float wC = k2 ? (float)__ushort_as_half((unsigned short)(eC >> 17)) : 0.f;
        float wD = k3 ? (float)__ushort_as_half((unsigned short)(eD >> 17)) : 0.f;
#pragma unroll
        for (int k = 0; k < 8; ++k) {
            acc[k] += wA * (float)vA[k];
            acc[k] += wB * (float)vB[k];
            acc[k] += wC * (float)vC[k];
            acc[k] += wD * (float)vD[k];
        }
    }

    // reduce over groups (lane bits 3,4,5): DPP ror8 + swizzle xor16 + shfl32
#pragma unroll
    for (int k = 0; k < 8; ++k) {
        float t = acc[k];
        t += dpp_ror8(t);
        t += swz_xor16(t);
        t += __shfl_xor(t, 32);
        acc[k] = t;
    }

    float di = dinv[wid];
    float4 bA = ((const float4*)b1)[s * 2], bB = ((const float4*)b1)[s * 2 + 1];
    float4 wA = ((const float4*)W2)[s * 2], wB = ((const float4*)W2)[s * 2 + 1];
    float p = 0.f;
    p += fmaxf(di * acc[0] + bA.x, 0.f) * wA.x;
    p += fmaxf(di * acc[1] + bA.y, 0.f) * wA.y;
    p += fmaxf(di * acc[2] + bA.z, 0.f) * wA.z;
    p += fmaxf(di * acc[3] + bA.w, 0.f) * wA.w;
    p += fmaxf(di * acc[4] + bB.x, 0.f) * wB.x;
    p += fmaxf(di * acc[5] + bB.y, 0.f) * wB.y;
    p += fmaxf(di * acc[6] + bB.z, 0.f) * wB.z;
    p += fmaxf(di * acc[7] + bB.w, 0.f) * wB.w;
    // reduce over s (lane bits 0,1,2): pure DPP
    p += dpp_mov<0xB1>(p);    // quad_perm [1,0,3,2] == xor 1
    p += dpp_mov<0x4E>(p);    // quad_perm [2,3,0,1] == xor 2
    p += dpp_mov<0x141>(p);   // row_half_mirror == xor 4 after 1,2 reduced
    if (lane == 0) h2s[wid] = di * p;
}

__global__ __launch_bounds__(256) void k_agg1_lo(const __half* __restrict__ hs,
                                                 const int* __restrict__ offset,
                                                 const unsigned* __restrict__ csr,
                                                 const float* __restrict__ dinv,
                                                 const float* __restrict__ b1,
                                                 const float* __restrict__ W2,
                                                 float* __restrict__ h2s,
                                                 int n0, int n1) {
    agg1_body(hs, offset, csr, dinv, b1, W2, h2s, n0, n1);
}

__global__ __launch_bounds__(256) void k_agg1_hi(const __half* __restrict__ hs,
                                                 const int* __restrict__ offset,
                                                 const unsigned* __restrict__ csr,
                                                 const float* __restrict__ dinv,
                                                 const float* __restrict__ b1,
                                                 const float* __restrict__ W2,
                                                 float* __restrict__ h2s,
                                                 int n0, int n1) {
    agg1_body(hs, offset, csr, dinv, b1, W2, h2s, n0, n1);
}

// ---------------- agg2 (identical to R24) ----------------

__global__ __launch_bounds__(256) void k_agg2(const float* __restrict__ h2s,
                                              const int* __restrict__ offset,
                                              const unsigned* __restrict__ csr,
                                              const float* __restrict__ dinv,
                                              const float* __restrict__ b2,
                                              float* __restrict__ out, int n) {
    int wid = __builtin_amdgcn_readfirstlane((int)((blockIdx.x * blockDim.x + threadIdx.x) >> 6));
    int lane = threadIdx.x & 63;
    if (wid >= n) return;
    int off0 = __builtin_amdgcn_readfirstlane(offset[wid]);
    int off1 = __builtin_amdgcn_readfirstlane(offset[wid + 1]);
    float di = dinv[wid];
    float p = 0.f;
    for (int e = off0 + lane; e < off1; e += 64) {
        unsigned ed = csr[e];
        p += (float)__ushort_as_half((unsigned short)(ed >> 17)) * h2s[ed & 0x1FFFF];
    }
#pragma unroll
    for (int s = 32; s > 0; s >>= 1) p += __shfl_xor(p, s);
    if (lane == 0) out[wid] = di * (p + h2s[wid]) + b2[0];
}

extern "C" void kernel_launch(void* const* d_in, const int* in_sizes, int n_in,
                              void* d_out, int out_size, void* d_ws, size_t ws_size,
                              hipStream_t stream) {
    const float* x  = (const float*)d_in[0];
    const int*   ei = (const int*)  d_in[1];
    const float* ea = (const float*)d_in[2];
    const float* W1 = (const float*)d_in[3];
    const float* b1 = (const float*)d_in[4];
    const float* W2 = (const float*)d_in[5];
    const float* b2 = (const float*)d_in[6];
    float* out = (float*)d_out;

    const int N  = in_sizes[0] / 128;   // 100000 (must be <= 131072)
    const int E  = in_sizes[2];         // 3200000
    const int E4 = E / 4;
    const int nbl  = (E4 + 2047) / 2048;        // 8192-edge chunks (391)
    const int nbkt = (N + BSIZE - 1) / BSIZE;   // active buckets (391)

    char* p = (char*)d_ws;
    auto alloc = [&](size_t bytes) -> void* {
        void* r = (void*)p;
        p += (bytes + 255) & ~(size_t)255;
        return r;
    };
    int*       gcnt   = (int*)      alloc((size_t)NBUCKET * 4);
    int2*      binned = (int2*)     alloc((size_t)NBUCKET * BCAP * 8);  // 39.8MB
    unsigned*  csr    = (unsigned*) alloc((size_t)E * 4);
    int*       offset = (int*)      alloc((size_t)(N + 1) * 4);
    float*     dinv   = (float*)    alloc((size_t)N * 4);
    __half*    hs     = (__half*)   alloc((size_t)N * 64 * 2);
    float*     h2s    = (float*)    alloc((size_t)N * 4);

    const int nb_gemm = (N + 63) / 64;
    const int Nh = N / 2;                         // 50000
    const int nb_lo = (Nh * 64 + 255) / 256;
    const int nb_hi = ((N - Nh) * 64 + 255) / 256;
    const int nb_wave = (N * 64 + 255) / 256;

    k_z512<<<1, 512, 0, stream>>>(gcnt);
    k_scatter1<<<nbl, 1024, 0, stream>>>(ei, ea, gcnt, binned, E, E4);
    k_finalize<<<nbkt, 1024, 0, stream>>>(binned, gcnt, csr, offset, dinv, N, E);
    k_gemm_mfma<<<nb_gemm, 256, 0, stream>>>(x, W1, dinv, hs, N);
    k_agg1_lo<<<nb_lo, 256, 0, stream>>>(hs, offset, csr, dinv, b1, W2, h2s, 0, Nh);
    k_agg1_hi<<<nb_hi, 256, 0, stream>>>(hs, offset, csr, dinv, b1, W2, h2s, Nh, N);
    k_agg2<<<nb_wave, 256, 0, stream>>>(h2s, offset, csr, dinv, b2, out, N);
}